// Round 1
// baseline (1971.592 us; speedup 1.0000x reference)
//
#include <hip/hip_runtime.h>

#define BN 262144
#define CD 64
#define FD 256

typedef short bf16x8 __attribute__((ext_vector_type(8)));
typedef float f32x4 __attribute__((ext_vector_type(4)));

#define MFMA(a, b, c) __builtin_amdgcn_mfma_f32_16x16x32_bf16((a), (b), (c), 0, 0, 0)

__device__ __forceinline__ unsigned short f2bf(float f) {
  union { float f; unsigned int u; } x; x.f = f;
  unsigned int u = x.u + 0x7fffu + ((x.u >> 16) & 1u);
  return (unsigned short)(u >> 16);
}
__device__ __forceinline__ float bf2f(unsigned int h) {
  union { unsigned int u; float f; } x; x.u = h << 16;
  return x.f;
}

// ws layout (ushort/bf16 units). Fragment-major arrays: elem((nt*KS+s)*64+lane)*8+j
// holds B[k][n] with n = nt*16 + (lane&15), k = s*32 + (lane>>4)*8 + j.
#define O_P1 0        // fwd G1: B[k][n] = W1[n*64+k]   (K=64,  N=256)
#define O_P2 16384    // fwd G2: B[k][n] = W2[n*256+k]  (K=256, N=256)
#define O_P3 81920    // fwd G3: B[k][n] = W3[n*256+k]  (K=256, N=64)
#define O_P4 98304    // bwd G4: B[k][n] = W3[k*256+n]  (K=64,  N=256)
#define O_P5 114688   // bwd G5: B[k][n] = W2[k*256+n]  (K=256, N=256) -> LDS
#define O_P6 180224   // bwd G6: B[k][n] = W1[k*64+n]   (K=256, N=64)
#define N_WS 196608

#define L_PING 131072  // LDS: [0,128K) = W2 frags, [128K,160K) = ping buffer

__global__ void invres_prep(const float* __restrict__ W1, const float* __restrict__ W2,
                            const float* __restrict__ W3, unsigned short* __restrict__ wsb) {
  int idx = blockIdx.x * 256 + threadIdx.x;
  if (idx >= N_WS) return;
  int j = idx & 7;
  int lane = (idx >> 3) & 63;
  int n16 = lane & 15;
  int k8 = (lane >> 4) * 8 + j;
  float val;
  if (idx < O_P2) {                 // P1, KS=2
    int g = idx >> 9; int s = g & 1; int nt = g >> 1;
    val = W1[(nt * 16 + n16) * 64 + (s * 32 + k8)];
  } else if (idx < O_P3) {          // P2, KS=8
    int g = (idx - O_P2) >> 9; int s = g & 7; int nt = g >> 3;
    val = W2[(nt * 16 + n16) * 256 + (s * 32 + k8)];
  } else if (idx < O_P4) {          // P3, KS=8
    int g = (idx - O_P3) >> 9; int s = g & 7; int nt = g >> 3;
    val = W3[(nt * 16 + n16) * 256 + (s * 32 + k8)];
  } else if (idx < O_P5) {          // P4, KS=2
    int g = (idx - O_P4) >> 9; int s = g & 1; int nt = g >> 1;
    val = W3[(s * 32 + k8) * 256 + (nt * 16 + n16)];
  } else if (idx < O_P6) {          // P5, KS=8
    int g = (idx - O_P5) >> 9; int s = g & 7; int nt = g >> 3;
    val = W2[(s * 32 + k8) * 256 + (nt * 16 + n16)];
  } else {                          // P6, KS=8
    int g = (idx - O_P6) >> 9; int s = g & 7; int nt = g >> 3;
    val = W1[(s * 32 + k8) * 64 + (nt * 16 + n16)];
  }
  wsb[idx] = f2bf(val);
}

__global__ void __launch_bounds__(512, 2)
invres_main(const float* __restrict__ y, const float* __restrict__ ldj,
            const float* __restrict__ v, const float* __restrict__ b1,
            const float* __restrict__ b2, const float* __restrict__ b3,
            const unsigned short* __restrict__ wsb, float* __restrict__ out) {
  extern __shared__ char smem[];
  const int tid = threadIdx.x;
  const int lane = tid & 63;
  const int wid = tid >> 6;      // 0..7
  const int m = wid >> 1;        // M-tile 0..3 (16 rows each)
  const int nh = wid & 1;        // N-half
  const int l16 = lane & 15;
  const int g16 = lane >> 4;
  const int kbase = g16 * 8;
  const int bid = blockIdx.x;
  const int r0 = bid * 64 + m * 16;

  // stage W2 bwd-fragments into LDS (layout identical to global P5)
  {
    const float4* src = (const float4*)(wsb + O_P5);
    float4* dst = (float4*)smem;
#pragma unroll
    for (int i = 0; i < 16; i++) dst[tid + i * 512] = src[tid + i * 512];
  }

  const bf16x8* P1 = (const bf16x8*)(wsb + O_P1);
  const bf16x8* P2 = (const bf16x8*)(wsb + O_P2);
  const bf16x8* P3 = (const bf16x8*)(wsb + O_P3);
  const bf16x8* P4 = (const bf16x8*)(wsb + O_P4);
  const bf16x8* P6 = (const bf16x8*)(wsb + O_P6);
  const bf16x8* L5 = (const bf16x8*)smem;

  const int arl = m * 16 + l16;                      // local A-row for frag reads
  const unsigned int xrA = (unsigned int)((arl & 7) << 4);

  // ---------------- forward ----------------
  bf16x8 h0A[2];
  {
    const float* yp = y + (size_t)(r0 + l16) * 64 + kbase;
#pragma unroll
    for (int s = 0; s < 2; s++) {
      float4 a = *(const float4*)(yp + s * 32);
      float4 b = *(const float4*)(yp + s * 32 + 4);
      float xv[8] = {a.x, a.y, a.z, a.w, b.x, b.y, b.z, b.w};
      bf16x8 f;
#pragma unroll
      for (int i = 0; i < 8; i++) {
        float x = xv[i];
        x = x > 0.f ? x : (__expf(x) - 1.f);
        f[i] = (short)f2bf(x);
      }
      h0A[s] = f;
    }
  }

  unsigned int d1p[8][2], d2p[8][2];

  // G1: a1 = h0 @ W1^T + b1 ; h1 = elu(a1) -> ping ; d1 = elu'(a1)
  {
    f32x4 acc[8] = {};
#pragma unroll
    for (int s = 0; s < 2; s++)
#pragma unroll
      for (int t = 0; t < 8; t++)
        acc[t] = MFMA(h0A[s], P1[((nh * 8 + t) * 2 + s) * 64 + lane], acc[t]);
#pragma unroll
    for (int t = 0; t < 8; t++) {
      int col = (nh * 8 + t) * 16 + l16;
      float bb = b1[col];
      unsigned int dd[4];
#pragma unroll
      for (int r = 0; r < 4; r++) {
        float a = acc[t][r] + bb;
        float e = __expf(a);
        float h = a > 0.f ? a : (e - 1.f);
        dd[r] = f2bf(a > 0.f ? 1.f : e);
        int row = m * 16 + g16 * 4 + r;
        *(unsigned short*)(smem + L_PING + row * 512 + (((unsigned)(col * 2)) ^ ((row & 7) << 4))) = f2bf(h);
      }
      d1p[t][0] = dd[0] | (dd[1] << 16);
      d1p[t][1] = dd[2] | (dd[3] << 16);
    }
  }
  __syncthreads();

  bf16x8 hA[8];
#pragma unroll
  for (int s = 0; s < 8; s++) {
    int k0 = s * 32 + kbase;
    hA[s] = *(const bf16x8*)(smem + L_PING + arl * 512 + (((unsigned)(k0 * 2)) ^ xrA));
  }
  __syncthreads();

  // G2: a2 = h1 @ W2^T + b2 ; h2 -> ping ; d2
  {
    f32x4 acc[8] = {};
#pragma unroll
    for (int s = 0; s < 8; s++)
#pragma unroll
      for (int t = 0; t < 8; t++)
        acc[t] = MFMA(hA[s], P2[((nh * 8 + t) * 8 + s) * 64 + lane], acc[t]);
#pragma unroll
    for (int t = 0; t < 8; t++) {
      int col = (nh * 8 + t) * 16 + l16;
      float bb = b2[col];
      unsigned int dd[4];
#pragma unroll
      for (int r = 0; r < 4; r++) {
        float a = acc[t][r] + bb;
        float e = __expf(a);
        float h = a > 0.f ? a : (e - 1.f);
        dd[r] = f2bf(a > 0.f ? 1.f : e);
        int row = m * 16 + g16 * 4 + r;
        *(unsigned short*)(smem + L_PING + row * 512 + (((unsigned)(col * 2)) ^ ((row & 7) << 4))) = f2bf(h);
      }
      d2p[t][0] = dd[0] | (dd[1] << 16);
      d2p[t][1] = dd[2] | (dd[3] << 16);
    }
  }
  __syncthreads();
#pragma unroll
  for (int s = 0; s < 8; s++) {
    int k0 = s * 32 + kbase;
    hA[s] = *(const bf16x8*)(smem + L_PING + arl * 512 + (((unsigned)(k0 * 2)) ^ xrA));
  }
  __syncthreads();

  // G3: g = h2 @ W3^T + b3 ; z = y + g ; also d0 = elu'(y), v0 in D-layout
  float d0v[2][4], v0q[2][4];
  {
    f32x4 acc[2] = {};
#pragma unroll
    for (int s = 0; s < 8; s++)
#pragma unroll
      for (int t2 = 0; t2 < 2; t2++)
        acc[t2] = MFMA(hA[s], P3[((nh * 2 + t2) * 8 + s) * 64 + lane], acc[t2]);
#pragma unroll
    for (int t2 = 0; t2 < 2; t2++) {
      int col = (nh * 2 + t2) * 16 + l16;
      float bb = b3[col];
#pragma unroll
      for (int r = 0; r < 4; r++) {
        int grow = r0 + g16 * 4 + r;
        size_t off = (size_t)grow * 64 + col;
        float yv = y[off];
        out[off] = yv + acc[t2][r] + bb;
        d0v[t2][r] = yv > 0.f ? 1.f : __expf(yv);
        v0q[t2][r] = v[off];
      }
    }
  }

  // w = v0 as A-fragments
  bf16x8 wA[2];
  {
    const float* vp = v + (size_t)(r0 + l16) * 64 + kbase;
#pragma unroll
    for (int s = 0; s < 2; s++) {
      float4 a = *(const float4*)(vp + s * 32);
      float4 b = *(const float4*)(vp + s * 32 + 4);
      float xv[8] = {a.x, a.y, a.z, a.w, b.x, b.y, b.z, b.w};
      bf16x8 f;
#pragma unroll
      for (int i = 0; i < 8; i++) f[i] = (short)f2bf(xv[i]);
      wA[s] = f;
    }
  }

  // ---------------- backward: 8 VJP iterations ----------------
  float ldacc[4] = {0.f, 0.f, 0.f, 0.f};
  for (int k = 1; k <= 8; ++k) {
    // G4: u2 = (w @ W3) * d2 -> ping
    {
      f32x4 acc[8] = {};
#pragma unroll
      for (int s = 0; s < 2; s++)
#pragma unroll
        for (int t = 0; t < 8; t++)
          acc[t] = MFMA(wA[s], P4[((nh * 8 + t) * 2 + s) * 64 + lane], acc[t]);
#pragma unroll
      for (int t = 0; t < 8; t++) {
        int col = (nh * 8 + t) * 16 + l16;
#pragma unroll
        for (int r = 0; r < 4; r++) {
          float dv = bf2f((d2p[t][r >> 1] >> ((r & 1) * 16)) & 0xffffu);
          float u = acc[t][r] * dv;
          int row = m * 16 + g16 * 4 + r;
          *(unsigned short*)(smem + L_PING + row * 512 + (((unsigned)(col * 2)) ^ ((row & 7) << 4))) = f2bf(u);
        }
      }
    }
    __syncthreads();
    bf16x8 uA[8];
#pragma unroll
    for (int s = 0; s < 8; s++) {
      int k0 = s * 32 + kbase;
      uA[s] = *(const bf16x8*)(smem + L_PING + arl * 512 + (((unsigned)(k0 * 2)) ^ xrA));
    }
    __syncthreads();
    // G5: u1 = (u2 @ W2) * d1 -> ping   (W2 frags from LDS)
    {
      f32x4 acc[8] = {};
#pragma unroll
      for (int s = 0; s < 8; s++)
#pragma unroll
        for (int t = 0; t < 8; t++)
          acc[t] = MFMA(uA[s], L5[((nh * 8 + t) * 8 + s) * 64 + lane], acc[t]);
#pragma unroll
      for (int t = 0; t < 8; t++) {
        int col = (nh * 8 + t) * 16 + l16;
#pragma unroll
        for (int r = 0; r < 4; r++) {
          float dv = bf2f((d1p[t][r >> 1] >> ((r & 1) * 16)) & 0xffffu);
          float u = acc[t][r] * dv;
          int row = m * 16 + g16 * 4 + r;
          *(unsigned short*)(smem + L_PING + row * 512 + (((unsigned)(col * 2)) ^ ((row & 7) << 4))) = f2bf(u);
        }
      }
    }
    __syncthreads();
#pragma unroll
    for (int s = 0; s < 8; s++) {
      int k0 = s * 32 + kbase;
      uA[s] = *(const bf16x8*)(smem + L_PING + arl * 512 + (((unsigned)(k0 * 2)) ^ xrA));
    }
    __syncthreads();
    // G6: w' = (u1 @ W1) * d0 ; inner += w'.v0 ; w' -> wbuf (64-col swizzled)
    {
      float coef = (k & 1) ? (1.f / (float)k) : (-1.f / (float)k);
      f32x4 acc[2] = {};
#pragma unroll
      for (int s = 0; s < 8; s++)
#pragma unroll
        for (int t2 = 0; t2 < 2; t2++)
          acc[t2] = MFMA(uA[s], P6[((nh * 2 + t2) * 8 + s) * 64 + lane], acc[t2]);
#pragma unroll
      for (int t2 = 0; t2 < 2; t2++) {
        int col = (nh * 2 + t2) * 16 + l16;
#pragma unroll
        for (int r = 0; r < 4; r++) {
          float wv = acc[t2][r] * d0v[t2][r];
          ldacc[r] += coef * wv * v0q[t2][r];
          if (k < 8) {
            int row = m * 16 + g16 * 4 + r;
            *(unsigned short*)(smem + L_PING + row * 128 + (((unsigned)(col * 2)) ^ ((row & 7) << 4))) = f2bf(wv);
          }
        }
      }
    }
    if (k < 8) {
      __syncthreads();
#pragma unroll
      for (int s = 0; s < 2; s++) {
        int k0 = s * 32 + kbase;
        wA[s] = *(const bf16x8*)(smem + L_PING + arl * 128 + (((unsigned)(k0 * 2)) ^ xrA));
      }
      __syncthreads();
    }
  }

  // ---------------- log-det epilogue ----------------
#pragma unroll
  for (int r = 0; r < 4; r++) {
    float s = ldacc[r];
    s += __shfl_xor(s, 1);
    s += __shfl_xor(s, 2);
    s += __shfl_xor(s, 4);
    s += __shfl_xor(s, 8);
    ldacc[r] = s;
  }
  if (l16 == 0) {
#pragma unroll
    for (int r = 0; r < 4; r++) {
      int rowl = m * 16 + g16 * 4 + r;
      *(float*)(smem + L_PING + (rowl * 2 + nh) * 4) = ldacc[r];
    }
  }
  __syncthreads();
  if (tid < 64) {
    float s = *(float*)(smem + L_PING + (tid * 2) * 4) +
              *(float*)(smem + L_PING + (tid * 2 + 1) * 4);
    int gb = bid * 64 + tid;
    out[(size_t)BN * 64 + gb] = ldj[gb] + s;
  }
}

extern "C" void kernel_launch(void* const* d_in, const int* in_sizes, int n_in,
                              void* d_out, int out_size, void* d_ws, size_t ws_size,
                              hipStream_t stream) {
  const float* y   = (const float*)d_in[0];
  const float* ldj = (const float*)d_in[1];
  const float* v   = (const float*)d_in[2];
  const float* W1  = (const float*)d_in[3];
  const float* b1  = (const float*)d_in[4];
  const float* W2  = (const float*)d_in[5];
  const float* b2  = (const float*)d_in[6];
  const float* W3  = (const float*)d_in[7];
  const float* b3  = (const float*)d_in[8];
  unsigned short* wsb = (unsigned short*)d_ws;
  float* out = (float*)d_out;

  (void)hipFuncSetAttribute(reinterpret_cast<const void*>(&invres_main),
                            hipFuncAttributeMaxDynamicSharedMemorySize, 163840);

  invres_prep<<<N_WS / 256, 256, 0, stream>>>(W1, W2, W3, wsb);
  invres_main<<<BN / 64, 512, 163840, stream>>>(y, ldj, v, b1, b2, b3, wsb, out);
}